// Round 6
// baseline (137.999 us; speedup 1.0000x reference)
//
#include <hip/hip_runtime.h>
#include <hip/hip_bf16.h>

#ifndef __has_builtin
#define __has_builtin(x) 0
#endif

#if __has_builtin(__builtin_amdgcn_exp2f)
#define FAST_EXP2(x) __builtin_amdgcn_exp2f(x)
#else
#define FAST_EXP2(x) exp2f(x)
#endif

#if __has_builtin(__builtin_amdgcn_sqrtf)
#define FAST_SQRT(x) __builtin_amdgcn_sqrtf(x)
#else
#define FAST_SQRT(x) sqrtf(x)
#endif

typedef float v2f __attribute__((ext_vector_type(2)));

// packed 2-wide helpers; guarded so worst case is scalar (same numerics)
#if __has_builtin(__builtin_elementwise_fma)
#define FMA2(a, b, c) __builtin_elementwise_fma((a), (b), (c))
#else
static __device__ __forceinline__ v2f FMA2(v2f a, v2f b, v2f c) {
  v2f r; r.x = fmaf(a.x, b.x, c.x); r.y = fmaf(a.y, b.y, c.y); return r;
}
#endif
#if __has_builtin(__builtin_elementwise_max)
#define MAX2(a, b) __builtin_elementwise_max((a), (b))
#else
static __device__ __forceinline__ v2f MAX2(v2f a, v2f b) {
  v2f r; r.x = fmaxf(a.x, b.x); r.y = fmaxf(a.y, b.y); return r;
}
#endif

// Problem constants (fixed by setup_inputs): B=8, M=N=4096, C=3
constexpr int kB = 8;
constexpr int kM = 4096;
constexpr int kN = 4096;
// softmin: exp(-d/T) = exp2(-C2*d), T=0.1; work in ds = C2*d via C2^2-scaled d^2
constexpr float C2  = 14.426950408889634f;
constexpr float C22 = C2 * C2;
// harness re-poisons d_ws to 0xAA bytes before every launch (stated contract)
#define POISON_U32 0xAAAAAAAAu   // as float: -3.03e-13 (harmless accum base)

constexpr int RPL    = 4;                 // pred rows per lane
constexpr int ROWS   = 64 * RPL;          // 256 rows per block
constexpr int WAVES  = 16;
constexpr int BLOCKT = 64 * WAVES;        // 1024 threads
constexpr int NROWG  = (kB * kM) / ROWS;  // 128 row groups
// ws layout: [0]=fp32 accum, [1]=ticket, [16..]=partials L[NS][32768], A[NS][32768]
constexpr int    PART_OFF = 16;
constexpr size_t ws_need(int ns) { return (size_t)(PART_OFF + 2 * ns * kB * kM) * 4; }

// ---------------- phase 1: per-(row, segment) softmin partials ----------------
// LDS holds gt-point PAIRS: gp[2k]={x0,x1,y0,y1}, gp[2k+1]={z0,z1,w0,w1},
// w = C2^2*|g|^2. Two broadcast ds_read_b128 yield packed operands directly.
template <int NSPLIT>
__global__ __launch_bounds__(BLOCKT, 8) void emd_partial_kernel(
    const float* __restrict__ pred, const float* __restrict__ gt,
    float* __restrict__ partL, float* __restrict__ partA) {
  constexpr int SEGN = kN / NSPLIT;     // gt points per block (even)
  constexpr int NPC  = SEGN / WAVES;    // gt points per wave
  __shared__ __align__(16) float4 gp[SEGN];     // pair records, 16B/point
  // [wv][r][lane]: lane-stride 1 -> conflict-free (verified R5: conflicts=0)
  __shared__ float red_l[WAVES][RPL][64];
  __shared__ float red_a[WAVES][RPL][64];

  const int tid  = threadIdx.x;
  const int lane = tid & 63;
  const int wv   = tid >> 6;
  const int rg   = blockIdx.x / NSPLIT;   // row group
  const int seg  = blockIdx.x % NSPLIT;   // gt segment
  const int rbase = rg * ROWS;
  const int b     = rbase >> 12;          // 256 | 4096 so no batch straddle

  // stage this block's gt segment into LDS as packed pairs
  const float* gtb = gt + ((size_t)b * kN + (size_t)seg * SEGN) * 3;
  for (int k = tid; k < SEGN / 2; k += BLOCKT) {
    const float* p = gtb + 6 * k;
    float x0 = p[0], y0 = p[1], z0 = p[2];
    float x1 = p[3], y1 = p[4], z1 = p[5];
    float w0 = C22 * fmaf(x0, x0, fmaf(y0, y0, z0 * z0));
    float w1 = C22 * fmaf(x1, x1, fmaf(y1, y1, z1 * z1));
    gp[2 * k]     = make_float4(x0, x1, y0, y1);
    gp[2 * k + 1] = make_float4(z0, z1, w0, w1);
  }
  // RPL pred rows per lane; coefficients splatted to both packed halves
  v2f nx2[RPL], ny2[RPL], nz2[RPL], pq2[RPL];
  const int m0 = (rbase & (kM - 1)) + lane;
#pragma unroll
  for (int r = 0; r < RPL; ++r) {
    const float* pp = pred + ((size_t)b * kM + m0 + r * 64) * 3;
    float x = pp[0], y = pp[1], z = pp[2];
    nx2[r] = -2.0f * C22 * x;
    ny2[r] = -2.0f * C22 * y;
    nz2[r] = -2.0f * C22 * z;
    pq2[r] = C22 * fmaf(x, x, fmaf(y, y, z * z));
  }
  __syncthreads();

  // fixed-reference softmin accumulation (d>=0 so exp2(-ds) in (0,1])
  v2f l2[RPL] = {};
  v2f a2[RPL] = {};
  const int k0 = wv * (NPC / 2);          // pair index base
  for (int k = k0; k < k0 + NPC / 2; k += 2) {
    const float4 qa0 = gp[2 * k],     qa1 = gp[2 * k + 1];
    const float4 qb0 = gp[2 * k + 2], qb1 = gp[2 * k + 3];
#define PBODY(Q0, Q1, r)                                            \
    {                                                               \
      v2f X2 = {Q0.x, Q0.y}, Y2 = {Q0.z, Q0.w};                     \
      v2f Z2 = {Q1.x, Q1.y}, W2 = {Q1.z, Q1.w};                     \
      v2f u = W2 + pq2[r];                                          \
      u = FMA2(nz2[r], Z2, u);                                      \
      u = FMA2(ny2[r], Y2, u);                                      \
      u = FMA2(nx2[r], X2, u);                                      \
      u = MAX2(u, (v2f)0.0f);                                       \
      float ds0 = FAST_SQRT(u.x), ds1 = FAST_SQRT(u.y);             \
      float p0  = FAST_EXP2(-ds0), p1 = FAST_EXP2(-ds1);            \
      v2f ds = {ds0, ds1}, pw = {p0, p1};                           \
      l2[r] += pw;                                                  \
      a2[r] = FMA2(ds, pw, a2[r]);                                  \
    }
#pragma unroll
    for (int r = 0; r < RPL; ++r) PBODY(qa0, qa1, r)
#pragma unroll
    for (int r = 0; r < RPL; ++r) PBODY(qb0, qb1, r)
#undef PBODY
  }
#pragma unroll
  for (int r = 0; r < RPL; ++r) {
    red_l[wv][r][lane] = l2[r].x + l2[r].y;
    red_a[wv][r][lane] = a2[r].x + a2[r].y;
  }
  __syncthreads();

  // combine the 16 waves' chunks; one thread per (r, lane) row
  if (tid < 64 * RPL) {
    const int ln = tid & 63, r = tid >> 6;
    float lt = 0.f, at = 0.f;
#pragma unroll
    for (int c = 0; c < WAVES; ++c) { lt += red_l[c][r][ln]; at += red_a[c][r][ln]; }
    const int row = rbase + r * 64 + ln;
    partL[(size_t)seg * (kB * kM) + row] = lt;
    partA[(size_t)seg * (kB * kM) + row] = at;
  }
}

// ---------------- phase 2: per-row divide + global mean ----------------
constexpr int CB      = 512;
constexpr int CBLOCKS = (kB * kM) / CB;   // 64
template <int NSEG>
__global__ __launch_bounds__(CB) void emd_combine_kernel(
    const float* __restrict__ partL, const float* __restrict__ partA,
    float* __restrict__ ws, float* __restrict__ out) {
  const int row = blockIdx.x * CB + threadIdx.x;
  float lt = 0.f, at = 0.f;
#pragma unroll
  for (int s = 0; s < NSEG; ++s) {
    lt += partL[(size_t)s * (kB * kM) + row];
    at += partA[(size_t)s * (kB * kM) + row];
  }
  // at/lt = C2 * softmin-weighted dist; undo C2 and fold the 1/(B*M) mean
  float w = (at / lt) * (1.0f / (C2 * (float)(kB * kM)));
#pragma unroll
  for (int off = 32; off > 0; off >>= 1) w += __shfl_down(w, off, 64);
  __shared__ float sred[CB / 64];
  const int lane = threadIdx.x & 63, wv = threadIdx.x >> 6;
  if (lane == 0) sred[wv] = w;
  __syncthreads();
  if (threadIdx.x == 0) {
    float s = 0.f;
#pragma unroll
    for (int i = 0; i < CB / 64; ++i) s += sred[i];
    // ws[0] starts at poison float(0xAAAAAAAA) = -3.03e-13 (negligible)
    atomicAdd(&ws[0], s);
    __threadfence();
    unsigned t = atomicAdd((unsigned int*)(ws + 1), 1u);
    if (t == POISON_U32 + (unsigned)(CBLOCKS - 1)) {
      __threadfence();
      out[0] = atomicAdd(&ws[0], 0.0f);   // device-coherent read; fp32 output
    }
  }
}

// ---------------- fallback (proven R3 kernel) if ws is too small ----------------
constexpr int F_CHUNKS  = 16;
constexpr int F_BLOCKT  = 64 * F_CHUNKS;
constexpr int F_NPC     = kN / F_CHUNKS;
constexpr int F_NBLOCKS = (kB * kM) / 64;

__global__ __launch_bounds__(F_BLOCKT, 8) void emd_softmin_fallback(
    const float* __restrict__ pred, const float* __restrict__ gt,
    float* __restrict__ ws, float* __restrict__ out) {
  __shared__ __align__(16) float4 g4[kN];
  __shared__ float red_l[F_CHUNKS][64];
  __shared__ float red_a[F_CHUNKS][64];
  const int tid = threadIdx.x, lane = tid & 63, chunk = tid >> 6;
  const int rbase = blockIdx.x * 64;
  const int b = rbase >> 12;
  const int m = (rbase & (kM - 1)) + lane;
  const float* gtb = gt + (size_t)b * kN * 3;
  for (int i = tid; i < kN; i += F_BLOCKT) {
    const float* p = gtb + 3 * i;
    float x = p[0], y = p[1], z = p[2];
    g4[i] = make_float4(x, y, z, C22 * fmaf(x, x, fmaf(y, y, z * z)));
  }
  const float* pp_ptr = pred + ((size_t)b * kM + (size_t)m) * 3;
  const float px = pp_ptr[0], py = pp_ptr[1], pz = pp_ptr[2];
  const float nx = -2.0f * C22 * px, ny = -2.0f * C22 * py, nz = -2.0f * C22 * pz;
  const float pq = C22 * fmaf(px, px, fmaf(py, py, pz * pz));
  __syncthreads();
  float l0 = 0.f, l1 = 0.f, a0 = 0.f, a1 = 0.f;
  const int n0 = chunk * F_NPC;
#pragma unroll 2
  for (int n = n0; n < n0 + F_NPC; n += 2) {
    const float4 G0 = g4[n], G1 = g4[n + 1];
    {
      float s = fmaf(nx, G0.x, fmaf(ny, G0.y, fmaf(nz, G0.z, G0.w + pq)));
      float ds = FAST_SQRT(fmaxf(s, 0.f));
      float p = FAST_EXP2(-ds);
      l0 += p; a0 = fmaf(ds, p, a0);
    }
    {
      float s = fmaf(nx, G1.x, fmaf(ny, G1.y, fmaf(nz, G1.z, G1.w + pq)));
      float ds = FAST_SQRT(fmaxf(s, 0.f));
      float p = FAST_EXP2(-ds);
      l1 += p; a1 = fmaf(ds, p, a1);
    }
  }
  red_l[chunk][lane] = l0 + l1;
  red_a[chunk][lane] = a0 + a1;
  __syncthreads();
  if (tid < 64) {
    float lt = 0.f, at = 0.f;
#pragma unroll
    for (int c = 0; c < F_CHUNKS; ++c) { lt += red_l[c][tid]; at += red_a[c][tid]; }
    float w = (at / lt) * (1.0f / (C2 * (float)(kB * kM)));
#pragma unroll
    for (int off = 32; off > 0; off >>= 1) w += __shfl_down(w, off, 64);
    if (tid == 0) {
      atomicAdd(&ws[0], w);
      __threadfence();
      unsigned t = atomicAdd((unsigned int*)(ws + 1), 1u);
      if (t == POISON_U32 + (unsigned)(F_NBLOCKS - 1)) {
        __threadfence();
        out[0] = atomicAdd(&ws[0], 0.0f);
      }
    }
  }
}

extern "C" void kernel_launch(void* const* d_in, const int* in_sizes, int n_in,
                              void* d_out, int out_size, void* d_ws, size_t ws_size,
                              hipStream_t stream) {
  const float* pred = (const float*)d_in[0];
  const float* gt   = (const float*)d_in[1];
  float* out = (float*)d_out;
  float* ws  = (float*)d_ws;

  // branch depends only on ws_size (call-invariant) -> graph-capture safe
  if (ws_size >= ws_need(4)) {
    float* partL = ws + PART_OFF;
    float* partA = partL + (size_t)4 * kB * kM;
    emd_partial_kernel<4><<<NROWG * 4, BLOCKT, 0, stream>>>(pred, gt, partL, partA);
    emd_combine_kernel<4><<<CBLOCKS, CB, 0, stream>>>(partL, partA, ws, out);
  } else if (ws_size >= ws_need(2)) {
    float* partL = ws + PART_OFF;
    float* partA = partL + (size_t)2 * kB * kM;
    emd_partial_kernel<2><<<NROWG * 2, BLOCKT, 0, stream>>>(pred, gt, partL, partA);
    emd_combine_kernel<2><<<CBLOCKS, CB, 0, stream>>>(partL, partA, ws, out);
  } else {
    emd_softmin_fallback<<<F_NBLOCKS, F_BLOCKT, 0, stream>>>(pred, gt, ws, out);
  }
}

// Round 7
// 93.855 us; speedup vs baseline: 1.4703x; 1.4703x over previous
//
#include <hip/hip_runtime.h>
#include <hip/hip_bf16.h>

#ifndef __has_builtin
#define __has_builtin(x) 0
#endif

#if __has_builtin(__builtin_amdgcn_exp2f)
#define FAST_EXP2(x) __builtin_amdgcn_exp2f(x)
#else
#define FAST_EXP2(x) exp2f(x)
#endif

#if __has_builtin(__builtin_amdgcn_sqrtf)
#define FAST_SQRT(x) __builtin_amdgcn_sqrtf(x)
#else
#define FAST_SQRT(x) sqrtf(x)
#endif

typedef float v2f __attribute__((ext_vector_type(2)));

#if __has_builtin(__builtin_elementwise_fma)
#define FMA2(a, b, c) __builtin_elementwise_fma((a), (b), (c))
#else
static __device__ __forceinline__ v2f FMA2(v2f a, v2f b, v2f c) {
  v2f r; r.x = fmaf(a.x, b.x, c.x); r.y = fmaf(a.y, b.y, c.y); return r;
}
#endif
#if __has_builtin(__builtin_elementwise_max)
#define MAX2(a, b) __builtin_elementwise_max((a), (b))
#else
static __device__ __forceinline__ v2f MAX2(v2f a, v2f b) {
  v2f r; r.x = fmaxf(a.x, b.x); r.y = fmaxf(a.y, b.y); return r;
}
#endif

// Problem constants (fixed by setup_inputs): B=8, M=N=4096, C=3
constexpr int kB = 8;
constexpr int kM = 4096;
constexpr int kN = 4096;
// softmin: exp(-d/T) = exp2(-C2*d), T=0.1; work in ds = C2*d via C2^2-scaled d^2
constexpr float C2  = 14.426950408889634f;
constexpr float C22 = C2 * C2;
// harness re-poisons d_ws to 0xAA bytes before every launch (stated contract)
#define POISON_U32 0xAAAAAAAAu   // as float: -3.03e-13 (harmless accum base)

constexpr int RPL    = 4;                 // pred rows per lane
constexpr int ROWS   = 64 * RPL;          // 256 rows per block
constexpr int WAVES  = 16;
constexpr int BLOCKT = 64 * WAVES;        // 1024 threads
constexpr int NROWG  = (kB * kM) / ROWS;  // 128 row groups
// ws layout: [0]=fp32 accum, [1]=ticket, [16..]=partials L[NS][32768], A[NS][32768]
constexpr int    PART_OFF = 16;
constexpr size_t ws_need(int ns) { return (size_t)(PART_OFF + 2 * ns * kB * kM) * 4; }

// ---------------- phase 1: per-(row, segment) softmin partials ----------------
// LDS gt-point PAIRS: gp[2k]={x0,x1,y0,y1}, gp[2k+1]={z0,z1,w0,w1}, w=C2^2|g|^2.
// R6 post-mortem: spill (FETCH 26MB/WRITE 46MB) from 64-VGPR cap -> min-waves=4
// (128 VGPR). Staging: ONE float4 per thread -> conflict-free (R6 had 65k).
template <int NSPLIT>
__global__ __launch_bounds__(BLOCKT, 4) void emd_partial_kernel(
    const float* __restrict__ pred, const float* __restrict__ gt,
    float* __restrict__ partL, float* __restrict__ partA) {
  constexpr int SEGN = kN / NSPLIT;     // gt points per block (even)
  constexpr int NPC  = SEGN / WAVES;    // gt points per wave
  __shared__ __align__(16) float4 gp[SEGN];     // pair records, 16B/point
  __shared__ float red_l[WAVES][RPL][64];       // lane-stride 1: conflict-free
  __shared__ float red_a[WAVES][RPL][64];

  const int tid  = threadIdx.x;
  const int lane = tid & 63;
  const int wv   = tid >> 6;
  const int rg   = blockIdx.x / NSPLIT;   // row group
  const int seg  = blockIdx.x % NSPLIT;   // gt segment
  const int rbase = rg * ROWS;
  const int b     = rbase >> 12;          // 256 | 4096 so no batch straddle

  // stage: thread i writes record i (consecutive lanes -> consecutive float4)
  const float* gtb = gt + ((size_t)b * kN + (size_t)seg * SEGN) * 3;
  for (int i = tid; i < SEGN; i += BLOCKT) {
    const int k = i >> 1;                 // pair index
    const float* p = gtb + 6 * k;         // both points of the pair (L2-hot)
    float x0 = p[0], y0 = p[1], z0 = p[2];
    float x1 = p[3], y1 = p[4], z1 = p[5];
    if (i & 1) {
      float w0 = C22 * fmaf(x0, x0, fmaf(y0, y0, z0 * z0));
      float w1 = C22 * fmaf(x1, x1, fmaf(y1, y1, z1 * z1));
      gp[i] = make_float4(z0, z1, w0, w1);
    } else {
      gp[i] = make_float4(x0, x1, y0, y1);
    }
  }
  // RPL pred rows per lane; scalar coefficients, splatted at use (op_sel)
  float nx[RPL], ny[RPL], nz[RPL], pq[RPL];
  const int m0 = (rbase & (kM - 1)) + lane;
#pragma unroll
  for (int r = 0; r < RPL; ++r) {
    const float* pp = pred + ((size_t)b * kM + m0 + r * 64) * 3;
    float x = pp[0], y = pp[1], z = pp[2];
    nx[r] = -2.0f * C22 * x;
    ny[r] = -2.0f * C22 * y;
    nz[r] = -2.0f * C22 * z;
    pq[r] = C22 * fmaf(x, x, fmaf(y, y, z * z));
  }
  __syncthreads();

  // fixed-reference softmin accumulation (d>=0 so exp2(-ds) in (0,1])
  v2f l2[RPL] = {};
  v2f a2[RPL] = {};
  const int k0 = wv * (NPC / 2);          // pair index base
  for (int k = k0; k < k0 + NPC / 2; k += 2) {
    const float4 qa0 = gp[2 * k],     qa1 = gp[2 * k + 1];
    const float4 qb0 = gp[2 * k + 2], qb1 = gp[2 * k + 3];
#define SPL(s) ((v2f){(s), (s)})
#define PBODY(Q0, Q1, r)                                            \
    {                                                               \
      v2f X2 = {Q0.x, Q0.y}, Y2 = {Q0.z, Q0.w};                     \
      v2f Z2 = {Q1.x, Q1.y}, W2 = {Q1.z, Q1.w};                     \
      v2f u = W2 + SPL(pq[r]);                                      \
      u = FMA2(SPL(nz[r]), Z2, u);                                  \
      u = FMA2(SPL(ny[r]), Y2, u);                                  \
      u = FMA2(SPL(nx[r]), X2, u);                                  \
      u = MAX2(u, (v2f)0.0f);                                       \
      float ds0 = FAST_SQRT(u.x), ds1 = FAST_SQRT(u.y);             \
      float p0  = FAST_EXP2(-ds0), p1 = FAST_EXP2(-ds1);            \
      v2f ds = {ds0, ds1}, pw = {p0, p1};                           \
      l2[r] += pw;                                                  \
      a2[r] = FMA2(ds, pw, a2[r]);                                  \
    }
#pragma unroll
    for (int r = 0; r < RPL; ++r) PBODY(qa0, qa1, r)
#pragma unroll
    for (int r = 0; r < RPL; ++r) PBODY(qb0, qb1, r)
#undef PBODY
#undef SPL
  }
#pragma unroll
  for (int r = 0; r < RPL; ++r) {
    red_l[wv][r][lane] = l2[r].x + l2[r].y;
    red_a[wv][r][lane] = a2[r].x + a2[r].y;
  }
  __syncthreads();

  // combine the 16 waves' chunks; one thread per (r, lane) row
  if (tid < 64 * RPL) {
    const int ln = tid & 63, r = tid >> 6;
    float lt = 0.f, at = 0.f;
#pragma unroll
    for (int c = 0; c < WAVES; ++c) { lt += red_l[c][r][ln]; at += red_a[c][r][ln]; }
    const int row = rbase + r * 64 + ln;
    partL[(size_t)seg * (kB * kM) + row] = lt;
    partA[(size_t)seg * (kB * kM) + row] = at;
  }
}

// ---------------- phase 2: per-row divide + global mean ----------------
constexpr int CB      = 512;
constexpr int CBLOCKS = (kB * kM) / CB;   // 64
template <int NSEG>
__global__ __launch_bounds__(CB) void emd_combine_kernel(
    const float* __restrict__ partL, const float* __restrict__ partA,
    float* __restrict__ ws, float* __restrict__ out) {
  const int row = blockIdx.x * CB + threadIdx.x;
  float lt = 0.f, at = 0.f;
#pragma unroll
  for (int s = 0; s < NSEG; ++s) {
    lt += partL[(size_t)s * (kB * kM) + row];
    at += partA[(size_t)s * (kB * kM) + row];
  }
  // at/lt = C2 * softmin-weighted dist; undo C2 and fold the 1/(B*M) mean
  float w = (at / lt) * (1.0f / (C2 * (float)(kB * kM)));
#pragma unroll
  for (int off = 32; off > 0; off >>= 1) w += __shfl_down(w, off, 64);
  __shared__ float sred[CB / 64];
  const int lane = threadIdx.x & 63, wv = threadIdx.x >> 6;
  if (lane == 0) sred[wv] = w;
  __syncthreads();
  if (threadIdx.x == 0) {
    float s = 0.f;
#pragma unroll
    for (int i = 0; i < CB / 64; ++i) s += sred[i];
    // ws[0] starts at poison float(0xAAAAAAAA) = -3.03e-13 (negligible)
    atomicAdd(&ws[0], s);
    __threadfence();
    unsigned t = atomicAdd((unsigned int*)(ws + 1), 1u);
    if (t == POISON_U32 + (unsigned)(CBLOCKS - 1)) {
      __threadfence();
      out[0] = atomicAdd(&ws[0], 0.0f);   // device-coherent read; fp32 output
    }
  }
}

// ---------------- fallback (proven R3 kernel) if ws is too small ----------------
constexpr int F_CHUNKS  = 16;
constexpr int F_BLOCKT  = 64 * F_CHUNKS;
constexpr int F_NPC     = kN / F_CHUNKS;
constexpr int F_NBLOCKS = (kB * kM) / 64;

__global__ __launch_bounds__(F_BLOCKT, 8) void emd_softmin_fallback(
    const float* __restrict__ pred, const float* __restrict__ gt,
    float* __restrict__ ws, float* __restrict__ out) {
  __shared__ __align__(16) float4 g4[kN];
  __shared__ float red_l[F_CHUNKS][64];
  __shared__ float red_a[F_CHUNKS][64];
  const int tid = threadIdx.x, lane = tid & 63, chunk = tid >> 6;
  const int rbase = blockIdx.x * 64;
  const int b = rbase >> 12;
  const int m = (rbase & (kM - 1)) + lane;
  const float* gtb = gt + (size_t)b * kN * 3;
  for (int i = tid; i < kN; i += F_BLOCKT) {
    const float* p = gtb + 3 * i;
    float x = p[0], y = p[1], z = p[2];
    g4[i] = make_float4(x, y, z, C22 * fmaf(x, x, fmaf(y, y, z * z)));
  }
  const float* pp_ptr = pred + ((size_t)b * kM + (size_t)m) * 3;
  const float px = pp_ptr[0], py = pp_ptr[1], pz = pp_ptr[2];
  const float nx = -2.0f * C22 * px, ny = -2.0f * C22 * py, nz = -2.0f * C22 * pz;
  const float pq = C22 * fmaf(px, px, fmaf(py, py, pz * pz));
  __syncthreads();
  float l0 = 0.f, l1 = 0.f, a0 = 0.f, a1 = 0.f;
  const int n0 = chunk * F_NPC;
#pragma unroll 2
  for (int n = n0; n < n0 + F_NPC; n += 2) {
    const float4 G0 = g4[n], G1 = g4[n + 1];
    {
      float s = fmaf(nx, G0.x, fmaf(ny, G0.y, fmaf(nz, G0.z, G0.w + pq)));
      float ds = FAST_SQRT(fmaxf(s, 0.f));
      float p = FAST_EXP2(-ds);
      l0 += p; a0 = fmaf(ds, p, a0);
    }
    {
      float s = fmaf(nx, G1.x, fmaf(ny, G1.y, fmaf(nz, G1.z, G1.w + pq)));
      float ds = FAST_SQRT(fmaxf(s, 0.f));
      float p = FAST_EXP2(-ds);
      l1 += p; a1 = fmaf(ds, p, a1);
    }
  }
  red_l[chunk][lane] = l0 + l1;
  red_a[chunk][lane] = a0 + a1;
  __syncthreads();
  if (tid < 64) {
    float lt = 0.f, at = 0.f;
#pragma unroll
    for (int c = 0; c < F_CHUNKS; ++c) { lt += red_l[c][tid]; at += red_a[c][tid]; }
    float w = (at / lt) * (1.0f / (C2 * (float)(kB * kM)));
#pragma unroll
    for (int off = 32; off > 0; off >>= 1) w += __shfl_down(w, off, 64);
    if (tid == 0) {
      atomicAdd(&ws[0], w);
      __threadfence();
      unsigned t = atomicAdd((unsigned int*)(ws + 1), 1u);
      if (t == POISON_U32 + (unsigned)(F_NBLOCKS - 1)) {
        __threadfence();
        out[0] = atomicAdd(&ws[0], 0.0f);
      }
    }
  }
}

extern "C" void kernel_launch(void* const* d_in, const int* in_sizes, int n_in,
                              void* d_out, int out_size, void* d_ws, size_t ws_size,
                              hipStream_t stream) {
  const float* pred = (const float*)d_in[0];
  const float* gt   = (const float*)d_in[1];
  float* out = (float*)d_out;
  float* ws  = (float*)d_ws;

  // branch depends only on ws_size (call-invariant) -> graph-capture safe
  if (ws_size >= ws_need(4)) {
    float* partL = ws + PART_OFF;
    float* partA = partL + (size_t)4 * kB * kM;
    emd_partial_kernel<4><<<NROWG * 4, BLOCKT, 0, stream>>>(pred, gt, partL, partA);
    emd_combine_kernel<4><<<CBLOCKS, CB, 0, stream>>>(partL, partA, ws, out);
  } else if (ws_size >= ws_need(2)) {
    float* partL = ws + PART_OFF;
    float* partA = partL + (size_t)2 * kB * kM;
    emd_partial_kernel<2><<<NROWG * 2, BLOCKT, 0, stream>>>(pred, gt, partL, partA);
    emd_combine_kernel<2><<<CBLOCKS, CB, 0, stream>>>(partL, partA, ws, out);
  } else {
    emd_softmin_fallback<<<F_NBLOCKS, F_BLOCKT, 0, stream>>>(pred, gt, ws, out);
  }
}